// Round 1
// baseline (234.448 us; speedup 1.0000x reference)
//
#include <hip/hip_runtime.h>
#include <math.h>

#define EPS 1e-5f

// XOR swizzle on 16B-granule index: involution, permutes granules only
// within their aligned 128B group (low 3 bits XOR'ed with bits 3..5).
__device__ __forceinline__ int swz(int a) { return a ^ ((a >> 3) & 7); }

// One block per (b,c) row. T=8192 floats = 2048 float4 granules.
// 512 threads (8 waves), 16 elements (4 granules) per thread.
// LDS = 32 KB linear granule array, logically XOR-swizzled:
//   slot s holds global granule swz(s)  (swz is an involution).
// Phase 1: global_load_lds width-16 DMA, linear LDS dest (wave-uniform
//   base + lane*16 as HW requires), pre-swizzled per-lane global source.
// Phase 2: each thread reads its 4 granules at swz(4t+j) (conflict-free:
//   each 4-bank group hit exactly 8x per wave = wave64 minimum),
//   block-scan of (sum,sumsq), sequential replay normalizes in-register,
//   writes back to the same swizzled slots.
// Phase 3: thread reads slot swz(j*512+t) (within-128B permutation of a
//   linear pattern -> conflict-free), stores coalesced.
__global__ __launch_bounds__(512, 8) void causal_ln_kernel(
    const float* __restrict__ x,
    const float* __restrict__ weight,
    const float* __restrict__ bias,
    float* __restrict__ out,
    int C, int T)
{
    __shared__ float lds[2048 * 4];      // 32 KB
    __shared__ float wsum[8], wsum2[8];

    const int row  = blockIdx.x;         // b*C + c
    const int c    = row % C;
    const float wv = weight[c];
    const float bv = bias[c];
    const long long base = (long long)row * (long long)T;

    const int t    = threadIdx.x;        // 0..511
    const int lane = t & 63;
    const int wid  = t >> 6;             // wave id 0..7

    // ---- Phase 1: async global->LDS DMA, pre-swizzled source ----
    const float* xrow = x + base;
#pragma unroll
    for (int j = 0; j < 4; ++j) {
        int slot = j * 512 + t;          // linear LDS granule this lane fills
        int g    = swz(slot);            // global granule whose data lands here
        const __attribute__((address_space(1))) float* gp =
            (const __attribute__((address_space(1))) float*)(xrow + g * 4);
        __attribute__((address_space(3))) float* lp =
            (__attribute__((address_space(3))) float*)(&lds[(j * 512 + (wid << 6)) * 4]);
        __builtin_amdgcn_global_load_lds(gp, lp, 16, 0, 0);
    }
    __syncthreads();                     // drains vmcnt before barrier

    // ---- Phase 2a: read own 4 granules (16 contiguous elements) ----
    float4 v[4];
#pragma unroll
    for (int j = 0; j < 4; ++j)
        v[j] = *(const float4*)&lds[swz(t * 4 + j) * 4];

    float s = 0.f, s2 = 0.f;
#pragma unroll
    for (int j = 0; j < 4; ++j) {
        s  += v[j].x + v[j].y + v[j].z + v[j].w;
        s2 += v[j].x * v[j].x + v[j].y * v[j].y
            + v[j].z * v[j].z + v[j].w * v[j].w;
    }

    // wave64 inclusive scan of (s, s2)
    float ws = s, ws2 = s2;
#pragma unroll
    for (int off = 1; off < 64; off <<= 1) {
        float a  = __shfl_up(ws,  off, 64);
        float a2 = __shfl_up(ws2, off, 64);
        if (lane >= off) { ws += a; ws2 += a2; }
    }

    // cross-wave combine (8 waves)
    if (lane == 63) { wsum[wid] = ws; wsum2[wid] = ws2; }
    __syncthreads();
    float off1 = 0.f, off2 = 0.f;
#pragma unroll
    for (int k = 0; k < 8; ++k) {
        if (k < wid) { off1 += wsum[k]; off2 += wsum2[k]; }
    }

    // exclusive prefix for this thread
    float es  = __shfl_up(ws,  1, 64);
    float es2 = __shfl_up(ws2, 1, 64);
    if (lane == 0) { es = 0.f; es2 = 0.f; }
    float run  = off1 + es;
    float run2 = off2 + es2;

    // ---- Phase 2b: sequential replay, normalize, write back ----
    float cnt = (float)(t * 16);
#pragma unroll
    for (int j = 0; j < 4; ++j) {
        float xs[4] = {v[j].x, v[j].y, v[j].z, v[j].w};
#pragma unroll
        for (int i = 0; i < 4; ++i) {
            float xi = xs[i];
            run  += xi;
            run2 += xi * xi;
            cnt  += 1.f;
            float rc   = __builtin_amdgcn_rcpf(cnt);
            float mean = run * rc;
            float var  = fmaxf(run2 * rc - mean * mean, 0.f);
            float rinv = __builtin_amdgcn_rsqf(var + EPS);
            xs[i] = (xi - mean) * rinv * wv + bv;
        }
        *(float4*)&lds[swz(t * 4 + j) * 4] =
            make_float4(xs[0], xs[1], xs[2], xs[3]);
    }
    __syncthreads();

    // ---- Phase 3: gather from swizzled slots, coalesced store ----
    float4* og = (float4*)(out + base);
#pragma unroll
    for (int j = 0; j < 4; ++j) {
        int g = j * 512 + t;             // output granule (coalesced store)
        og[g] = *(const float4*)&lds[swz(g) * 4];
    }
}

extern "C" void kernel_launch(void* const* d_in, const int* in_sizes, int n_in,
                              void* d_out, int out_size, void* d_ws, size_t ws_size,
                              hipStream_t stream) {
    const float* x      = (const float*)d_in[0];
    const float* weight = (const float*)d_in[1];
    const float* bias   = (const float*)d_in[2];
    float* out          = (float*)d_out;

    const int C = in_sizes[1];            // 512 (weight is [1,C,1])
    const int T = 8192;                   // time length per row
    const int rows = in_sizes[0] / T;     // B*C = 4096

    dim3 grid(rows), block(512);
    hipLaunchKernelGGL(causal_ln_kernel, grid, block, 0, stream,
                       x, weight, bias, out, C, T);
}